// Round 15
// baseline (69.339 us; speedup 1.0000x reference)
//
#include <hip/hip_runtime.h>
#include <hip/hip_bf16.h>

// Problem constants (fixed by the reference)
#define Bb 4
#define Tt 2048
#define Dd 256
#define Hh 8
#define Mm (Bb * Tt)   // 8192

typedef __attribute__((ext_vector_type(8))) short short8v;   // 8 x bf16
typedef __attribute__((ext_vector_type(4))) short short4v;
typedef __attribute__((ext_vector_type(4))) float f32x4;
typedef __attribute__((ext_vector_type(4))) unsigned uint4v;

#define MFMA16(a, b, c) __builtin_amdgcn_mfma_f32_16x16x32_bf16(a, b, c, 0, 0, 0)

// async global->LDS, 16B per lane; LDS dest is wave-uniform base + lane*16
__device__ __forceinline__ void gload16(const void* g, void* l) {
  __builtin_amdgcn_global_load_lds((const __attribute__((address_space(1))) void*)g,
                                   (__attribute__((address_space(3))) void*)l, 16, 0, 0);
}

// f32 -> bf16 via compiler intrinsic (RNE; compiler pairs into v_cvt_pk_bf16_f32)
__device__ __forceinline__ short bfc(float f) {
  __hip_bfloat16 h = __float2bfloat16(f);
  return *reinterpret_cast<short*>(&h);
}
// pack two f32 -> two bf16 (truncation) in ONE v_perm_b32 (hot-loop P pack;
// proven R2-R14 — do NOT replace with inline-asm cvt_pk, m240/R7 regression)
__device__ __forceinline__ unsigned pk2bf(float lo, float hi) {
  union { float f; unsigned u; } a, b; a.f = lo; b.f = hi;
  return __builtin_amdgcn_perm(b.u, a.u, 0x07060302u);
}

// ---------------------------------------------------------------------------
// Kernel 1: fused 5-way projection GEMM.  Y_p = X_p @ W_p^T (bf16 out)
// 128x128 tiles, BK=64 (was 32): same staging bytes + MFMA count, HALF the
// __syncthreads (8 vs 16 per block). LDS 2x128x72 shorts = 36KB (pad 72:
// row stride 144B -> 2-way bank alias = free per m136). p==0/3 pre-scaled
// by HD^-0.5*log2(e). p==2 (V) -> transposed Vt[(b*8+h)*32+d][t].
// ---------------------------------------------------------------------------
__global__ __launch_bounds__(256)
void proj_kernel(const float* __restrict__ content, const float* __restrict__ category,
                 const float* __restrict__ Wqc, const float* __restrict__ Wkc,
                 const float* __restrict__ Wv, const float* __restrict__ Wqk,
                 const float* __restrict__ Wkk, short* __restrict__ ws) {
  __shared__ short Al[128][72];
  __shared__ short Bl[128][72];

  const int mt = blockIdx.x;            // 0..63
  const int nt = blockIdx.y;            // 0..9
  const int p  = nt >> 1;               // projection index
  const int n0 = (nt & 1) << 7;

  const float* X = (p < 3) ? content : category;
  const float* W = (p == 0) ? Wqc : (p == 1) ? Wkc : (p == 2) ? Wv : (p == 3) ? Wqk : Wkk;
  short* Y = ws + (size_t)p * ((size_t)Mm * Dd);
  const float oscale = (p == 0 || p == 3)
      ? (0.17677669529663689f * 1.4426950408889634f) : 1.0f;

  const int tid  = threadIdx.x;
  const int lane = tid & 63;
  const int wv   = tid >> 6;
  const int wm   = (wv >> 1) << 6;
  const int wn   = (wv & 1) << 6;
  const int l15  = lane & 15;
  const int l4   = lane >> 4;

  const f32x4 zero = {0.f, 0.f, 0.f, 0.f};
  f32x4 acc[4][4];
#pragma unroll
  for (int i = 0; i < 4; i++)
#pragma unroll
    for (int j = 0; j < 4; j++) acc[i][j] = zero;

  const int rs = tid >> 4;              // 0..15 (staging row within pass)
  const int cs = (tid & 15) << 2;       // 0..60 (f32 cols)

  for (int k0 = 0; k0 < Dd; k0 += 64) {
#pragma unroll
    for (int pass = 0; pass < 8; pass++) {
      const int r = rs + (pass << 4);
      const float4 va = *reinterpret_cast<const float4*>(&X[(size_t)(mt * 128 + r) * Dd + k0 + cs]);
      short4v sa; sa[0] = bfc(va.x); sa[1] = bfc(va.y); sa[2] = bfc(va.z); sa[3] = bfc(va.w);
      *reinterpret_cast<short4v*>(&Al[r][cs]) = sa;
      const float4 vb = *reinterpret_cast<const float4*>(&W[(size_t)(n0 + r) * Dd + k0 + cs]);
      short4v sb; sb[0] = bfc(vb.x); sb[1] = bfc(vb.y); sb[2] = bfc(vb.z); sb[3] = bfc(vb.w);
      *reinterpret_cast<short4v*>(&Bl[r][cs]) = sb;
    }
    __syncthreads();

#pragma unroll
    for (int ks = 0; ks < 2; ks++) {
      const int kc = ks * 32 + l4 * 8;
      short8v af[4], bfr[4];
#pragma unroll
      for (int i = 0; i < 4; i++)
        af[i] = *reinterpret_cast<const short8v*>(&Al[wm + i * 16 + l15][kc]);
#pragma unroll
      for (int j = 0; j < 4; j++)
        bfr[j] = *reinterpret_cast<const short8v*>(&Bl[wn + j * 16 + l15][kc]);
#pragma unroll
      for (int i = 0; i < 4; i++)
#pragma unroll
        for (int j = 0; j < 4; j++)
          acc[i][j] = MFMA16(af[i], bfr[j], acc[i][j]);
    }
    __syncthreads();
  }

  if (p == 2) {
    // transposed V: Vt[(b*8+h)*32+d][t], pack 4 consecutive tokens per b64
#pragma unroll
    for (int i = 0; i < 4; i++) {
      const int trow = mt * 128 + wm + i * 16 + (l4 << 2);
      const int bidx = trow >> 11;
      const int tloc = trow & 2047;
#pragma unroll
      for (int j = 0; j < 4; j++) {
        const int cg = n0 + wn + j * 16 + l15;
        const int hh = cg >> 5, dd2 = cg & 31;
        short4v pk;
#pragma unroll
        for (int e = 0; e < 4; e++) pk[e] = bfc(acc[i][j][e]);
        *reinterpret_cast<short4v*>(&Y[((size_t)(bidx * 8 + hh) * 32 + dd2) * Tt + tloc]) = pk;
      }
    }
  } else {
#pragma unroll
    for (int i = 0; i < 4; i++) {
      const int rb = mt * 128 + wm + i * 16 + (l4 << 2);
#pragma unroll
      for (int j = 0; j < 4; j++) {
        const int c = n0 + wn + j * 16 + l15;
#pragma unroll
        for (int e = 0; e < 4; e++)
          Y[(size_t)(rb + e) * Dd + c] = bfc(acc[i][j][e] * oscale);
      }
    }
  }
}

// ---------------------------------------------------------------------------
// Kernel 2: dual causal flash attention — R11-EXACT (session-best: attn 43.2,
// total 68.26, absmax 0.0156, VGPR 52, no spill). R10 structure + MFMA
// row-sum. 1024 blocks x 512 threads: block = (bh, ONE q-tile qt),
// LPT-ordered, bh in low 5 bits. 2 K-parity groups of 4 waves, private
// double-buffered LDS (global_load_lds, sigma-permuted + XOR-swizzled src).
// sigma: LDS K slot 16f+4g+e holds kv 32(f&1)+8g+4(f>>1)+e => packed QK^T
// D-frag IS the PV A-frag. No-max softmax => additive parity combine.
// UNIFORM trip count. (512,4): VGPR cap 64. Plateau note: R12 diet, R13
// 4-wave, R14 counted-vmcnt all neutral-or-worse — this is the structure's
// measured optimum.
// ---------------------------------------------------------------------------
__global__ __launch_bounds__(512, 4)
void attn_kernel(const short* __restrict__ Qc, const short* __restrict__ Kc,
                 const short* __restrict__ Vt, const short* __restrict__ Qk,
                 const short* __restrict__ Kk, short* __restrict__ AO,
                 const float* __restrict__ alpha_p) {
  // per-group 24KB: Kc[2][64][32] @0, Kk @8K, Vt[2][32][64] @16K; x2 groups
  __shared__ __align__(16) char ldsraw[49152];

  const int bid = blockIdx.x;           // bh in low 5 bits -> XCD locality
  const int bh  = bid & 31;
  const int qt  = 31 - (bid >> 5);      // LPT: heaviest q-tiles first
  const int b = bh >> 3, h = bh & 7;
  const size_t rowbase = (size_t)b * Tt;
  const short* __restrict__ Vh  = Vt + (size_t)bh * 32 * Tt;
  const short* __restrict__ KcB = Kc + rowbase * Dd + h * 32;
  const short* __restrict__ KkB = Kk + rowbase * Dd + h * 32;

  const int tid  = threadIdx.x;
  const int lane = tid & 63;
  const int grp  = tid >> 8;            // K-parity group 0/1
  const int tg   = tid & 255;
  const int wq   = (tid >> 6) & 3;      // wave-in-group (q-rows 16*wq..+15)
  const int l15  = lane & 15, g = lane >> 4;

  char* gb = ldsraw + grp * 24576;

  // staging: slot = LDS K row; source row = sigma^{-1}(slot); chunk XOR-swizzled
  const int slot = tg >> 2;                                      // 0..63
  const int ksrc = ((slot >> 4) & 1) * 32 + ((slot >> 2) & 3) * 8
                 + (slot >> 5) * 4 + (slot & 3);                 // actual kv row
  const int kcg  = (tg & 3) ^ ((slot >> 1) & 3);
  const int vrow = tg >> 3;                                      // 0..31 (d)
  const int vcg  = (tg & 7) ^ (vrow & 7);

  // jt-invariant LDS read offsets (shorts)
  const int koff  = l15 * 32 + ((g ^ ((l15 >> 1) & 3)) << 3);    // +f*512
  const int voff0 = l15 * 64 + (((g) ^ (l15 & 7)) << 3);         // a=0, +n*1024
  const int voff1 = l15 * 64 + (((4 + g) ^ (l15 & 7)) << 3);     // a=1

  const float alpha = 1.f / (1.f + __builtin_amdgcn_exp2f(-alpha_p[0] * 1.4426950408889634f));
  const f32x4 zf = {0.f, 0.f, 0.f, 0.f};

  // all-ones bf16 B-fragment for the MFMA row-sum
  short8v onesf;
#pragma unroll
  for (int i = 0; i < 8; i++) onesf[i] = (short)0x3F80;

  // Q fragments, both streams (q=l15, d=8g..)
  const size_t qoff = (rowbase + (qt << 6) + wq * 16 + l15) * (size_t)Dd + h * 32 + g * 8;
  const short8v qcf = *(const short8v*)&Qc[qoff];   // pre-scaled by scale*log2e
  const short8v qkf = *(const short8v*)&Qk[qoff];

  f32x4 ov[2][2];                       // [stream][n]
  f32x4 lsv[2];                         // [stream] rowsum (same row map as ov)
#pragma unroll
  for (int s = 0; s < 2; s++) { ov[s][0] = zf; ov[s][1] = zf; lsv[s] = zf; }

  // first stage: jt = grp into buffer 0 (grp1's tile unused if qt==0; harmless)
  {
    const size_t k0s = (size_t)(grp << 6);
    gload16(KcB + (k0s + ksrc) * Dd + kcg * 8, gb + wq * 1024);
    gload16(KkB + (k0s + ksrc) * Dd + kcg * 8, gb + 8192 + wq * 1024);
    gload16(Vh + (size_t)vrow * Tt + k0s + vcg * 8, gb + 16384 + wq * 1024);
  }
  __syncthreads();

  // running prefetch pointers (jt+2 ahead)
  const short* kcPf = KcB + ((size_t)((grp + 2) << 6) + ksrc) * Dd + kcg * 8;
  const short* kkPf = KkB + ((size_t)((grp + 2) << 6) + ksrc) * Dd + kcg * 8;
  const short* vtPf = Vh + (size_t)vrow * Tt + ((grp + 2) << 6) + vcg * 8;
  const size_t kstep = (size_t)128 * Dd;

  // UNIFORM trip count across both parity groups (barrier safety).
  const int nIter = (qt >> 1) + 1;
  int jt = grp;
  for (int it = 0; it < nIter; ++it, jt += 2) {
    const int cur = it & 1;
    if (jt + 2 <= qt) {
      char* db = gb + (cur ^ 1) * 4096 + wq * 1024;
      gload16(kcPf, db);
      gload16(kkPf, db + 8192);
      gload16(vtPf, db + 16384);
      kcPf += kstep; kkPf += kstep; vtPf += 128;
    }
    if (jt <= qt) {
      const short* kcl = (const short*)(gb + cur * 4096);
      const short* kkl = (const short*)(gb + 8192 + cur * 4096);
      const short* vtl = (const short*)(gb + 16384 + cur * 4096);

      // V fragments (shared by both streams): vb[n][a]
      const short8v vb00 = *(const short8v*)(vtl + voff0);
      const short8v vb10 = *(const short8v*)(vtl + voff0 + 1024);
      const short8v vb01 = *(const short8v*)(vtl + voff1);
      const short8v vb11 = *(const short8v*)(vtl + voff1 + 1024);

      const bool diag = (jt == qt);
      const bool full = !diag || (wq >= 2);       // all 4 frags / both halves
#pragma unroll
      for (int s = 0; s < 2; s++) {
        const short* kl = s ? kkl : kcl;
        const short8v qf = s ? qkf : qcf;
        f32x4 sf[4];
#pragma unroll
        for (int f = 0; f < 4; f++) {
          if (((f & 1) == 0) || full) {
            const short8v kf = *(const short8v*)(kl + koff + f * 512);
            sf[f] = MFMA16(kf, qf, zf);           // D[kv'][q]: slot 16f+4g+e, q=l15
          }
        }
        if (diag) {
          const int thb = 16 * wq + l15 - 8 * g;
#pragma unroll
          for (int f = 0; f < 4; f++) {
            if (((f & 1) == 0) || full) {
              const int thr = thb - 32 * (f & 1) - 4 * (f >> 1);
#pragma unroll
              for (int e = 0; e < 4; e++)
                if (e > thr) sf[f][e] = -1e30f;   // exp2 -> 0
            }
          }
        }
#pragma unroll
        for (int f = 0; f < 4; f++) {
          if (((f & 1) == 0) || full) {
#pragma unroll
            for (int e = 0; e < 4; e++)
              sf[f][e] = __builtin_amdgcn_exp2f(sf[f][e]);
          }
        }

        // sigma layout => packed D IS the PV A-frag (kv half a: frags {a, a+2})
        union { uint4v u; short8v s8; } pa;
        pa.u = (uint4v){pk2bf(sf[0][0], sf[0][1]), pk2bf(sf[0][2], sf[0][3]),
                        pk2bf(sf[2][0], sf[2][1]), pk2bf(sf[2][2], sf[2][3])};
        __builtin_amdgcn_s_setprio(1);
        ov[s][0] = MFMA16(pa.s8, vb00, ov[s][0]);
        ov[s][1] = MFMA16(pa.s8, vb10, ov[s][1]);
        lsv[s]   = MFMA16(pa.s8, onesf, lsv[s]);  // rowsum on matrix pipe
        __builtin_amdgcn_s_setprio(0);
        if (full) {
          pa.u = (uint4v){pk2bf(sf[1][0], sf[1][1]), pk2bf(sf[1][2], sf[1][3]),
                          pk2bf(sf[3][0], sf[3][1]), pk2bf(sf[3][2], sf[3][3])};
          __builtin_amdgcn_s_setprio(1);
          ov[s][0] = MFMA16(pa.s8, vb01, ov[s][0]);
          ov[s][1] = MFMA16(pa.s8, vb11, ov[s][1]);
          lsv[s]   = MFMA16(pa.s8, onesf, lsv[s]);
          __builtin_amdgcn_s_setprio(0);
        }
      }
    }
    __syncthreads();   // prefetch landed + all reads of cur done (uniform count)
  }

  // ---- additive cross-parity combine (once; no-max softmax => exact) ----
  // per lane: 2 streams x {ov0, ov1, lsv} = 24 f32; stride 25 (odd -> no conflict)
  float* sp = (float*)ldsraw + (size_t)(wq * 64 + lane) * 25;
  if (grp == 1) {
#pragma unroll
    for (int s = 0; s < 2; s++) {
      *(f32x4*)(sp + s * 12)     = ov[s][0];
      *(f32x4*)(sp + s * 12 + 4) = ov[s][1];
      *(f32x4*)(sp + s * 12 + 8) = lsv[s];
    }
  }
  __syncthreads();
  if (grp == 0) {
#pragma unroll
    for (int s = 0; s < 2; s++) {
      ov[s][0] += *(const f32x4*)(sp + s * 12);
      ov[s][1] += *(const f32x4*)(sp + s * 12 + 4);
      lsv[s]   += *(const f32x4*)(sp + s * 12 + 8);
    }
    const size_t orow = rowbase + (qt << 6) + wq * 16 + g * 4;
#pragma unroll
    for (int n = 0; n < 2; n++)
#pragma unroll
      for (int e = 0; e < 4; e++) {
        const float o = ov[0][n][e] * ((1.f - alpha) / lsv[0][e])
                      + ov[1][n][e] * (alpha / lsv[1][e]);
        AO[(orow + e) * Dd + h * 32 + n * 16 + l15] = bfc(o);
      }
  }
}

// ---------------------------------------------------------------------------
// Kernel 3: output projection  out = AO @ Wo^T + bo  (f32 out), 64x64 tiles
// (unchanged)
// ---------------------------------------------------------------------------
__global__ __launch_bounds__(256)
void outproj_kernel(const short* __restrict__ AO, const float* __restrict__ Wo,
                    const float* __restrict__ bo, float* __restrict__ out) {
  __shared__ short Al[64][40];
  __shared__ short Bl[64][40];

  const int mt = blockIdx.x;          // 0..127
  const int n0 = (int)blockIdx.y << 6;

  const int tid  = threadIdx.x;
  const int lane = tid & 63;
  const int wv   = tid >> 6;
  const int wm   = (wv >> 1) << 5;
  const int wn   = (wv & 1) << 5;
  const int l15  = lane & 15;
  const int g    = lane >> 4;

  const f32x4 zero = {0.f, 0.f, 0.f, 0.f};
  f32x4 acc[2][2] = {{zero, zero}, {zero, zero}};

  const int ra = tid >> 2, ca = (tid & 3) << 3;
  const int rb = tid >> 3, cb = (tid & 7) << 2;

  for (int k0 = 0; k0 < Dd; k0 += 32) {
    *reinterpret_cast<short8v*>(&Al[ra][ca]) =
        *reinterpret_cast<const short8v*>(&AO[(size_t)(mt * 64 + ra) * Dd + k0 + ca]);
#pragma unroll
    for (int pass = 0; pass < 2; pass++) {
      const int r = rb + (pass << 5);
      const float4 vb = *reinterpret_cast<const float4*>(&Wo[(size_t)(n0 + r) * Dd + k0 + cb]);
      short4v sb; sb[0] = bfc(vb.x); sb[1] = bfc(vb.y); sb[2] = bfc(vb.z); sb[3] = bfc(vb.w);
      *reinterpret_cast<short4v*>(&Bl[r][cb]) = sb;
    }
    __syncthreads();

    short8v af[2], bf2[2];
#pragma unroll
    for (int i = 0; i < 2; i++)
      af[i] = *reinterpret_cast<const short8v*>(&Al[wm + i * 16 + l15][g * 8]);
#pragma unroll
    for (int j = 0; j < 2; j++)
      bf2[j] = *reinterpret_cast<const short8v*>(&Bl[wn + j * 16 + l15][g * 8]);
#pragma unroll
    for (int i = 0; i < 2; i++)
#pragma unroll
      for (int j = 0; j < 2; j++)
        acc[i][j] = MFMA16(af[i], bf2[j], acc[i][j]);
    __syncthreads();
  }

#pragma unroll
  for (int i = 0; i < 2; i++) {
    const int r0w = mt * 64 + wm + i * 16 + (g << 2);
#pragma unroll
    for (int j = 0; j < 2; j++) {
      const int c = n0 + wn + j * 16 + l15;
      const float bias = bo[c];
#pragma unroll
      for (int e = 0; e < 4; e++)
        out[(size_t)(r0w + e) * Dd + c] = acc[i][j][e] + bias;
    }
  }
}

// ---------------------------------------------------------------------------
extern "C" void kernel_launch(void* const* d_in, const int* in_sizes, int n_in,
                              void* d_out, int out_size, void* d_ws, size_t ws_size,
                              hipStream_t stream) {
  const float* content = (const float*)d_in[0];
  const float* category = (const float*)d_in[1];
  const float* Wqc = (const float*)d_in[2];
  const float* Wkc = (const float*)d_in[3];
  const float* Wv  = (const float*)d_in[4];
  const float* Wqk = (const float*)d_in[5];
  const float* Wkk = (const float*)d_in[6];
  const float* Wo  = (const float*)d_in[7];
  const float* bo  = (const float*)d_in[8];
  const float* alpha_logit = (const float*)d_in[9];
  float* out = (float*)d_out;

  short* ws = (short*)d_ws;
  const size_t buf = (size_t)Mm * Dd;   // 2M bf16 = 4MB per buffer
  short* Qc = ws + 0 * buf;             // pre-scaled by scale*log2e
  short* Kc = ws + 1 * buf;
  short* Vt = ws + 2 * buf;             // transposed: [(b*8+h)*32+d][t]
  short* Qk = ws + 3 * buf;             // pre-scaled
  short* Kk = ws + 4 * buf;
  short* AO = ws + 5 * buf;             // 24MB of d_ws total

  proj_kernel<<<dim3(64, 10), 256, 0, stream>>>(content, category, Wqc, Wkc, Wv, Wqk, Wkk, ws);
  attn_kernel<<<dim3(1024), 512, 0, stream>>>(Qc, Kc, Vt, Qk, Kk, AO, alpha_logit);
  outproj_kernel<<<dim3(128, 4), 256, 0, stream>>>(AO, Wo, bo, out);
}

// Round 16
// 68.166 us; speedup vs baseline: 1.0172x; 1.0172x over previous
//
#include <hip/hip_runtime.h>
#include <hip/hip_bf16.h>

// Problem constants (fixed by the reference)
#define Bb 4
#define Tt 2048
#define Dd 256
#define Hh 8
#define Mm (Bb * Tt)   // 8192

typedef __attribute__((ext_vector_type(8))) short short8v;   // 8 x bf16
typedef __attribute__((ext_vector_type(4))) short short4v;
typedef __attribute__((ext_vector_type(4))) float f32x4;
typedef __attribute__((ext_vector_type(4))) unsigned uint4v;

#define MFMA16(a, b, c) __builtin_amdgcn_mfma_f32_16x16x32_bf16(a, b, c, 0, 0, 0)

// async global->LDS, 16B per lane; LDS dest is wave-uniform base + lane*16
__device__ __forceinline__ void gload16(const void* g, void* l) {
  __builtin_amdgcn_global_load_lds((const __attribute__((address_space(1))) void*)g,
                                   (__attribute__((address_space(3))) void*)l, 16, 0, 0);
}

// f32 -> bf16 via compiler intrinsic (RNE; compiler pairs into v_cvt_pk_bf16_f32)
__device__ __forceinline__ short bfc(float f) {
  __hip_bfloat16 h = __float2bfloat16(f);
  return *reinterpret_cast<short*>(&h);
}
// pack two f32 -> two bf16 (truncation) in ONE v_perm_b32 (hot-loop P pack;
// proven R2-R15 — do NOT replace with inline-asm cvt_pk, m240/R7 regression)
__device__ __forceinline__ unsigned pk2bf(float lo, float hi) {
  union { float f; unsigned u; } a, b; a.f = lo; b.f = hi;
  return __builtin_amdgcn_perm(b.u, a.u, 0x07060302u);
}

// ---------------------------------------------------------------------------
// Kernel 1: fused 5-way projection GEMM.  Y_p = X_p @ W_p^T (bf16 out)
// R11-exact: 128x128 tiles, BK=32 (R15's BK=64 measured neutral-to-worse).
// p==0/3 (Qc/Qk) pre-scaled by HD^-0.5*log2(e) (folded attn scale).
// p==2 (V) writes TRANSPOSED per-head: Vt[(b*8+h)*32+d][t]
// ---------------------------------------------------------------------------
__global__ __launch_bounds__(256)
void proj_kernel(const float* __restrict__ content, const float* __restrict__ category,
                 const float* __restrict__ Wqc, const float* __restrict__ Wkc,
                 const float* __restrict__ Wv, const float* __restrict__ Wqk,
                 const float* __restrict__ Wkk, short* __restrict__ ws) {
  __shared__ short Al[128][40];
  __shared__ short Bl[128][40];

  const int mt = blockIdx.x;            // 0..63
  const int nt = blockIdx.y;            // 0..9
  const int p  = nt >> 1;               // projection index
  const int n0 = (nt & 1) << 7;

  const float* X = (p < 3) ? content : category;
  const float* W = (p == 0) ? Wqc : (p == 1) ? Wkc : (p == 2) ? Wv : (p == 3) ? Wqk : Wkk;
  short* Y = ws + (size_t)p * ((size_t)Mm * Dd);
  const float oscale = (p == 0 || p == 3)
      ? (0.17677669529663689f * 1.4426950408889634f) : 1.0f;

  const int tid  = threadIdx.x;
  const int lane = tid & 63;
  const int wv   = tid >> 6;
  const int wm   = (wv >> 1) << 6;
  const int wn   = (wv & 1) << 6;
  const int l15  = lane & 15;
  const int l4   = lane >> 4;

  const f32x4 zero = {0.f, 0.f, 0.f, 0.f};
  f32x4 acc[4][4];
#pragma unroll
  for (int i = 0; i < 4; i++)
#pragma unroll
    for (int j = 0; j < 4; j++) acc[i][j] = zero;

  const int rs = tid >> 3;
  const int cs = (tid & 7) << 2;

  for (int k0 = 0; k0 < Dd; k0 += 32) {
#pragma unroll
    for (int pass = 0; pass < 4; pass++) {
      const int r = rs + (pass << 5);
      const float4 va = *reinterpret_cast<const float4*>(&X[(size_t)(mt * 128 + r) * Dd + k0 + cs]);
      short4v sa; sa[0] = bfc(va.x); sa[1] = bfc(va.y); sa[2] = bfc(va.z); sa[3] = bfc(va.w);
      *reinterpret_cast<short4v*>(&Al[r][cs]) = sa;
      const float4 vb = *reinterpret_cast<const float4*>(&W[(size_t)(n0 + r) * Dd + k0 + cs]);
      short4v sb; sb[0] = bfc(vb.x); sb[1] = bfc(vb.y); sb[2] = bfc(vb.z); sb[3] = bfc(vb.w);
      *reinterpret_cast<short4v*>(&Bl[r][cs]) = sb;
    }
    __syncthreads();

    short8v af[4], bfr[4];
#pragma unroll
    for (int i = 0; i < 4; i++)
      af[i] = *reinterpret_cast<const short8v*>(&Al[wm + i * 16 + l15][l4 * 8]);
#pragma unroll
    for (int j = 0; j < 4; j++)
      bfr[j] = *reinterpret_cast<const short8v*>(&Bl[wn + j * 16 + l15][l4 * 8]);
#pragma unroll
    for (int i = 0; i < 4; i++)
#pragma unroll
      for (int j = 0; j < 4; j++)
        acc[i][j] = MFMA16(af[i], bfr[j], acc[i][j]);
    __syncthreads();
  }

  if (p == 2) {
    // transposed V: Vt[(b*8+h)*32+d][t], pack 4 consecutive tokens per b64
#pragma unroll
    for (int i = 0; i < 4; i++) {
      const int trow = mt * 128 + wm + i * 16 + (l4 << 2);
      const int bidx = trow >> 11;
      const int tloc = trow & 2047;
#pragma unroll
      for (int j = 0; j < 4; j++) {
        const int cg = n0 + wn + j * 16 + l15;
        const int hh = cg >> 5, dd2 = cg & 31;
        short4v pk;
#pragma unroll
        for (int e = 0; e < 4; e++) pk[e] = bfc(acc[i][j][e]);
        *reinterpret_cast<short4v*>(&Y[((size_t)(bidx * 8 + hh) * 32 + dd2) * Tt + tloc]) = pk;
      }
    }
  } else {
#pragma unroll
    for (int i = 0; i < 4; i++) {
      const int rb = mt * 128 + wm + i * 16 + (l4 << 2);
#pragma unroll
      for (int j = 0; j < 4; j++) {
        const int c = n0 + wn + j * 16 + l15;
#pragma unroll
        for (int e = 0; e < 4; e++)
          Y[(size_t)(rb + e) * Dd + c] = bfc(acc[i][j][e] * oscale);
      }
    }
  }
}

// ---------------------------------------------------------------------------
// Kernel 2: dual causal flash attention — R11-EXACT (session best: total
// 68.26us, attn 43.2us, absmax 0.0156, VGPR 52, no spill).
// 1024 blocks x 512 threads: block = (bh, ONE q-tile qt), LPT-ordered,
// bh in low 5 bits (XCD/L2 locality). 2 K-parity groups of 4 waves, private
// double-buffered LDS (global_load_lds, sigma-permuted + XOR-swizzled src).
// sigma: LDS K slot 16f+4g+e holds kv 32(f&1)+8g+4(f>>1)+e => packed QK^T
// D-frag IS the PV A-frag (zero cross-lane traffic). No-max softmax (inputs
// bounded) => additive parity combine. MFMA(P, ones) row-sum on the idle
// matrix pipe. UNIFORM trip count (barrier safety). (512,4): VGPR cap 64.
// PLATEAU (documented): R8/R10/R12/R13/R14 structural variants all land
// 42.4-43.7us; VALU-issue+dependency bound (VALUBusy*dur ~= 23.5us
// invariant, MfmaUtil 15%, HBM 7%). Next step would be producer-consumer
// wave specialization (full rewrite), not increments.
// ---------------------------------------------------------------------------
__global__ __launch_bounds__(512, 4)
void attn_kernel(const short* __restrict__ Qc, const short* __restrict__ Kc,
                 const short* __restrict__ Vt, const short* __restrict__ Qk,
                 const short* __restrict__ Kk, short* __restrict__ AO,
                 const float* __restrict__ alpha_p) {
  // per-group 24KB: Kc[2][64][32] @0, Kk @8K, Vt[2][32][64] @16K; x2 groups
  __shared__ __align__(16) char ldsraw[49152];

  const int bid = blockIdx.x;           // bh in low 5 bits -> XCD locality
  const int bh  = bid & 31;
  const int qt  = 31 - (bid >> 5);      // LPT: heaviest q-tiles first
  const int b = bh >> 3, h = bh & 7;
  const size_t rowbase = (size_t)b * Tt;
  const short* __restrict__ Vh  = Vt + (size_t)bh * 32 * Tt;
  const short* __restrict__ KcB = Kc + rowbase * Dd + h * 32;
  const short* __restrict__ KkB = Kk + rowbase * Dd + h * 32;

  const int tid  = threadIdx.x;
  const int lane = tid & 63;
  const int grp  = tid >> 8;            // K-parity group 0/1
  const int tg   = tid & 255;
  const int wq   = (tid >> 6) & 3;      // wave-in-group (q-rows 16*wq..+15)
  const int l15  = lane & 15, g = lane >> 4;

  char* gb = ldsraw + grp * 24576;

  // staging: slot = LDS K row; source row = sigma^{-1}(slot); chunk XOR-swizzled
  const int slot = tg >> 2;                                      // 0..63
  const int ksrc = ((slot >> 4) & 1) * 32 + ((slot >> 2) & 3) * 8
                 + (slot >> 5) * 4 + (slot & 3);                 // actual kv row
  const int kcg  = (tg & 3) ^ ((slot >> 1) & 3);
  const int vrow = tg >> 3;                                      // 0..31 (d)
  const int vcg  = (tg & 7) ^ (vrow & 7);

  // jt-invariant LDS read offsets (shorts)
  const int koff  = l15 * 32 + ((g ^ ((l15 >> 1) & 3)) << 3);    // +f*512
  const int voff0 = l15 * 64 + (((g) ^ (l15 & 7)) << 3);         // a=0, +n*1024
  const int voff1 = l15 * 64 + (((4 + g) ^ (l15 & 7)) << 3);     // a=1

  const float alpha = 1.f / (1.f + __builtin_amdgcn_exp2f(-alpha_p[0] * 1.4426950408889634f));
  const f32x4 zf = {0.f, 0.f, 0.f, 0.f};

  // all-ones bf16 B-fragment for the MFMA row-sum
  short8v onesf;
#pragma unroll
  for (int i = 0; i < 8; i++) onesf[i] = (short)0x3F80;

  // Q fragments, both streams (q=l15, d=8g..)
  const size_t qoff = (rowbase + (qt << 6) + wq * 16 + l15) * (size_t)Dd + h * 32 + g * 8;
  const short8v qcf = *(const short8v*)&Qc[qoff];   // pre-scaled by scale*log2e
  const short8v qkf = *(const short8v*)&Qk[qoff];

  f32x4 ov[2][2];                       // [stream][n]
  f32x4 lsv[2];                         // [stream] rowsum (same row map as ov)
#pragma unroll
  for (int s = 0; s < 2; s++) { ov[s][0] = zf; ov[s][1] = zf; lsv[s] = zf; }

  // first stage: jt = grp into buffer 0 (grp1's tile unused if qt==0; harmless)
  {
    const size_t k0s = (size_t)(grp << 6);
    gload16(KcB + (k0s + ksrc) * Dd + kcg * 8, gb + wq * 1024);
    gload16(KkB + (k0s + ksrc) * Dd + kcg * 8, gb + 8192 + wq * 1024);
    gload16(Vh + (size_t)vrow * Tt + k0s + vcg * 8, gb + 16384 + wq * 1024);
  }
  __syncthreads();

  // running prefetch pointers (jt+2 ahead)
  const short* kcPf = KcB + ((size_t)((grp + 2) << 6) + ksrc) * Dd + kcg * 8;
  const short* kkPf = KkB + ((size_t)((grp + 2) << 6) + ksrc) * Dd + kcg * 8;
  const short* vtPf = Vh + (size_t)vrow * Tt + ((grp + 2) << 6) + vcg * 8;
  const size_t kstep = (size_t)128 * Dd;

  // UNIFORM trip count across both parity groups (barrier safety).
  const int nIter = (qt >> 1) + 1;
  int jt = grp;
  for (int it = 0; it < nIter; ++it, jt += 2) {
    const int cur = it & 1;
    if (jt + 2 <= qt) {
      char* db = gb + (cur ^ 1) * 4096 + wq * 1024;
      gload16(kcPf, db);
      gload16(kkPf, db + 8192);
      gload16(vtPf, db + 16384);
      kcPf += kstep; kkPf += kstep; vtPf += 128;
    }
    if (jt <= qt) {
      const short* kcl = (const short*)(gb + cur * 4096);
      const short* kkl = (const short*)(gb + 8192 + cur * 4096);
      const short* vtl = (const short*)(gb + 16384 + cur * 4096);

      // V fragments (shared by both streams): vb[n][a]
      const short8v vb00 = *(const short8v*)(vtl + voff0);
      const short8v vb10 = *(const short8v*)(vtl + voff0 + 1024);
      const short8v vb01 = *(const short8v*)(vtl + voff1);
      const short8v vb11 = *(const short8v*)(vtl + voff1 + 1024);

      const bool diag = (jt == qt);
      const bool full = !diag || (wq >= 2);       // all 4 frags / both halves
#pragma unroll
      for (int s = 0; s < 2; s++) {
        const short* kl = s ? kkl : kcl;
        const short8v qf = s ? qkf : qcf;
        f32x4 sf[4];
#pragma unroll
        for (int f = 0; f < 4; f++) {
          if (((f & 1) == 0) || full) {
            const short8v kf = *(const short8v*)(kl + koff + f * 512);
            sf[f] = MFMA16(kf, qf, zf);           // D[kv'][q]: slot 16f+4g+e, q=l15
          }
        }
        if (diag) {
          const int thb = 16 * wq + l15 - 8 * g;
#pragma unroll
          for (int f = 0; f < 4; f++) {
            if (((f & 1) == 0) || full) {
              const int thr = thb - 32 * (f & 1) - 4 * (f >> 1);
#pragma unroll
              for (int e = 0; e < 4; e++)
                if (e > thr) sf[f][e] = -1e30f;   // exp2 -> 0
            }
          }
        }
#pragma unroll
        for (int f = 0; f < 4; f++) {
          if (((f & 1) == 0) || full) {
#pragma unroll
            for (int e = 0; e < 4; e++)
              sf[f][e] = __builtin_amdgcn_exp2f(sf[f][e]);
          }
        }

        // sigma layout => packed D IS the PV A-frag (kv half a: frags {a, a+2})
        union { uint4v u; short8v s8; } pa;
        pa.u = (uint4v){pk2bf(sf[0][0], sf[0][1]), pk2bf(sf[0][2], sf[0][3]),
                        pk2bf(sf[2][0], sf[2][1]), pk2bf(sf[2][2], sf[2][3])};
        __builtin_amdgcn_s_setprio(1);
        ov[s][0] = MFMA16(pa.s8, vb00, ov[s][0]);
        ov[s][1] = MFMA16(pa.s8, vb10, ov[s][1]);
        lsv[s]   = MFMA16(pa.s8, onesf, lsv[s]);  // rowsum on matrix pipe
        __builtin_amdgcn_s_setprio(0);
        if (full) {
          pa.u = (uint4v){pk2bf(sf[1][0], sf[1][1]), pk2bf(sf[1][2], sf[1][3]),
                          pk2bf(sf[3][0], sf[3][1]), pk2bf(sf[3][2], sf[3][3])};
          __builtin_amdgcn_s_setprio(1);
          ov[s][0] = MFMA16(pa.s8, vb01, ov[s][0]);
          ov[s][1] = MFMA16(pa.s8, vb11, ov[s][1]);
          lsv[s]   = MFMA16(pa.s8, onesf, lsv[s]);
          __builtin_amdgcn_s_setprio(0);
        }
      }
    }
    __syncthreads();   // prefetch landed + all reads of cur done (uniform count)
  }

  // ---- additive cross-parity combine (once; no-max softmax => exact) ----
  // per lane: 2 streams x {ov0, ov1, lsv} = 24 f32; stride 25 (odd -> no conflict)
  float* sp = (float*)ldsraw + (size_t)(wq * 64 + lane) * 25;
  if (grp == 1) {
#pragma unroll
    for (int s = 0; s < 2; s++) {
      *(f32x4*)(sp + s * 12)     = ov[s][0];
      *(f32x4*)(sp + s * 12 + 4) = ov[s][1];
      *(f32x4*)(sp + s * 12 + 8) = lsv[s];
    }
  }
  __syncthreads();
  if (grp == 0) {
#pragma unroll
    for (int s = 0; s < 2; s++) {
      ov[s][0] += *(const f32x4*)(sp + s * 12);
      ov[s][1] += *(const f32x4*)(sp + s * 12 + 4);
      lsv[s]   += *(const f32x4*)(sp + s * 12 + 8);
    }
    const size_t orow = rowbase + (qt << 6) + wq * 16 + g * 4;
#pragma unroll
    for (int n = 0; n < 2; n++)
#pragma unroll
      for (int e = 0; e < 4; e++) {
        const float o = ov[0][n][e] * ((1.f - alpha) / lsv[0][e])
                      + ov[1][n][e] * (alpha / lsv[1][e]);
        AO[(orow + e) * Dd + h * 32 + n * 16 + l15] = bfc(o);
      }
  }
}

// ---------------------------------------------------------------------------
// Kernel 3: output projection  out = AO @ Wo^T + bo  (f32 out), 64x64 tiles
// (unchanged)
// ---------------------------------------------------------------------------
__global__ __launch_bounds__(256)
void outproj_kernel(const short* __restrict__ AO, const float* __restrict__ Wo,
                    const float* __restrict__ bo, float* __restrict__ out) {
  __shared__ short Al[64][40];
  __shared__ short Bl[64][40];

  const int mt = blockIdx.x;          // 0..127
  const int n0 = (int)blockIdx.y << 6;

  const int tid  = threadIdx.x;
  const int lane = tid & 63;
  const int wv   = tid >> 6;
  const int wm   = (wv >> 1) << 5;
  const int wn   = (wv & 1) << 5;
  const int l15  = lane & 15;
  const int g    = lane >> 4;

  const f32x4 zero = {0.f, 0.f, 0.f, 0.f};
  f32x4 acc[2][2] = {{zero, zero}, {zero, zero}};

  const int ra = tid >> 2, ca = (tid & 3) << 3;
  const int rb = tid >> 3, cb = (tid & 7) << 2;

  for (int k0 = 0; k0 < Dd; k0 += 32) {
    *reinterpret_cast<short8v*>(&Al[ra][ca]) =
        *reinterpret_cast<const short8v*>(&AO[(size_t)(mt * 64 + ra) * Dd + k0 + ca]);
#pragma unroll
    for (int pass = 0; pass < 2; pass++) {
      const int r = rb + (pass << 5);
      const float4 vb = *reinterpret_cast<const float4*>(&Wo[(size_t)(n0 + r) * Dd + k0 + cb]);
      short4v sb; sb[0] = bfc(vb.x); sb[1] = bfc(vb.y); sb[2] = bfc(vb.z); sb[3] = bfc(vb.w);
      *reinterpret_cast<short4v*>(&Bl[r][cb]) = sb;
    }
    __syncthreads();

    short8v af[2], bf2[2];
#pragma unroll
    for (int i = 0; i < 2; i++)
      af[i] = *reinterpret_cast<const short8v*>(&Al[wm + i * 16 + l15][g * 8]);
#pragma unroll
    for (int j = 0; j < 2; j++)
      bf2[j] = *reinterpret_cast<const short8v*>(&Bl[wn + j * 16 + l15][g * 8]);
#pragma unroll
    for (int i = 0; i < 2; i++)
#pragma unroll
      for (int j = 0; j < 2; j++)
        acc[i][j] = MFMA16(af[i], bf2[j], acc[i][j]);
    __syncthreads();
  }

#pragma unroll
  for (int i = 0; i < 2; i++) {
    const int r0w = mt * 64 + wm + i * 16 + (g << 2);
#pragma unroll
    for (int j = 0; j < 2; j++) {
      const int c = n0 + wn + j * 16 + l15;
      const float bias = bo[c];
#pragma unroll
      for (int e = 0; e < 4; e++)
        out[(size_t)(r0w + e) * Dd + c] = acc[i][j][e] + bias;
    }
  }
}

// ---------------------------------------------------------------------------
extern "C" void kernel_launch(void* const* d_in, const int* in_sizes, int n_in,
                              void* d_out, int out_size, void* d_ws, size_t ws_size,
                              hipStream_t stream) {
  const float* content = (const float*)d_in[0];
  const float* category = (const float*)d_in[1];
  const float* Wqc = (const float*)d_in[2];
  const float* Wkc = (const float*)d_in[3];
  const float* Wv  = (const float*)d_in[4];
  const float* Wqk = (const float*)d_in[5];
  const float* Wkk = (const float*)d_in[6];
  const float* Wo  = (const float*)d_in[7];
  const float* bo  = (const float*)d_in[8];
  const float* alpha_logit = (const float*)d_in[9];
  float* out = (float*)d_out;

  short* ws = (short*)d_ws;
  const size_t buf = (size_t)Mm * Dd;   // 2M bf16 = 4MB per buffer
  short* Qc = ws + 0 * buf;             // pre-scaled by scale*log2e
  short* Kc = ws + 1 * buf;
  short* Vt = ws + 2 * buf;             // transposed: [(b*8+h)*32+d][t]
  short* Qk = ws + 3 * buf;             // pre-scaled
  short* Kk = ws + 4 * buf;
  short* AO = ws + 5 * buf;             // 24MB of d_ws total

  proj_kernel<<<dim3(64, 10), 256, 0, stream>>>(content, category, Wqc, Wkc, Wv, Wqk, Wkk, ws);
  attn_kernel<<<dim3(1024), 512, 0, stream>>>(Qc, Kc, Vt, Qk, Kk, AO, alpha_logit);
  outproj_kernel<<<dim3(128, 4), 256, 0, stream>>>(AO, Wo, bo, out);
}